// Round 2
// baseline (41937.915 us; speedup 1.0000x reference)
//
#include <hip/hip_runtime.h>

// LSTM_15556371546645 — MI355X (gfx950), round 2
// Chunked pipeline (8 chunks x 256 steps) to keep workspace ~53 MiB:
//   prep -> per chunk: enc GEMM (fp32 A staged->bf16) -> xg0 GEMM -> rec0
//                      -> xg1 GEMM -> rec1 -> dec GEMM (fp32 out)
// Recurrence: 4 wgs per layer, W_hh slice in LDS+VGPR MFMA fragments,
// per-step h all-gather via device-scope atomics (parity double buffer +
// monotone absolute-step flags, release on publish). c-state persisted in ws.

typedef unsigned short u16;
typedef unsigned long long u64;
typedef __attribute__((ext_vector_type(8))) short short8;   // 8 x bf16 (4 VGPRs)
typedef __attribute__((ext_vector_type(4))) float f32x4;    // MFMA acc

#define SEQ  2048
#define CS   256            // chunk steps
#define NCH  (SEQ / CS)     // 8 chunks
#define CN   (CS * 64)      // rows per chunk (S*B slice) = 16384

// ---------------- numeric helpers ----------------
__device__ __forceinline__ u16 f2bf(float f) {
  unsigned u = __float_as_uint(f);
  unsigned r = u + 0x7fffu + ((u >> 16) & 1u);   // RTNE
  return (u16)(r >> 16);
}
__device__ __forceinline__ float bf2f(u16 h) {
  return __uint_as_float(((unsigned)h) << 16);
}
__device__ __forceinline__ float sigf(float x) {
  return __builtin_amdgcn_rcpf(1.f + __expf(-x));
}
__device__ __forceinline__ float tanhf_fast(float x) {
  return 1.f - 2.f * __builtin_amdgcn_rcpf(1.f + __expf(2.f * x));
}

// ---------------- prep: convert + permute + pack ----------------
#define S1 16384     // enc_w -> bf16
#define S2 16384     // dec_w -> bf16
#define S3 524288    // w_ih permuted rows (r' = q*256 + g*64 + j  <- r = g*256 + q*64 + j)
#define S4 2048      // bias_perm = b_ih + b_hh (permuted rows)
#define S5 524288    // w_hh packed into MFMA B-fragment order per (layer, q)
#define S6 16        // flags zero
#define PREP_TOTAL (S1 + S2 + S3 + S4 + S5 + S6)

__global__ void prep_kernel(const float* __restrict__ enc_w,
                            const float* __restrict__ w_ih, const float* __restrict__ w_hh,
                            const float* __restrict__ b_ih, const float* __restrict__ b_hh,
                            const float* __restrict__ dec_w,
                            u16* __restrict__ WENC, u16* __restrict__ WDEC,
                            u16* __restrict__ WIH, float* __restrict__ BIASP,
                            u16* __restrict__ WHH, int* __restrict__ FLAGS)
{
  size_t idx = (size_t)blockIdx.x * 256 + threadIdx.x;
  if (idx < S1) { WENC[idx] = f2bf(enc_w[idx]); return; }
  idx -= S1;
  if (idx < S2) { WDEC[idx] = f2bf(dec_w[idx]); return; }
  idx -= S2;
  if (idx < S3) {   // W_ih row-permuted, bf16.  dst flat = [l][r'][k]
    int l = (int)(idx >> 18);
    int rem = (int)(idx & 262143);
    int rp = rem >> 8, k = rem & 255;
    int q = rp >> 8, g = (rp >> 6) & 3, j = rp & 63;
    int r = g * 256 + q * 64 + j;
    WIH[idx] = f2bf(w_ih[(size_t)l * 262144 + (size_t)r * 256 + k]);
    return;
  }
  idx -= S3;
  if (idx < S4) {   // bias_perm[l][r'] = b_ih[l][r] + b_hh[l][r]
    int l = (int)(idx >> 10);
    int rp = (int)(idx & 1023);
    int q = rp >> 8, g = (rp >> 6) & 3, j = rp & 63;
    int r = g * 256 + q * 64 + j;
    BIASP[idx] = b_ih[l * 1024 + r] + b_hh[l * 1024 + r];
    return;
  }
  idx -= S4;
  if (idx < S5) {   // W_hh fragment-packed. per (l,q) block = 65536 u16.
    int l = (int)(idx >> 18);
    int rem_a = (int)(idx & 262143);
    int q = rem_a >> 16;
    int rem2 = rem_a & 65535;
    int g, w, kc, ln, e;
    if (rem2 < 16384) {               // LDS part: kc 0..1: (((g*4+w)*2+kc)*64+ln)*8+e
      e = rem2 & 7;
      int slot = rem2 >> 3;
      ln = slot & 63;
      int kcgw = slot >> 6;
      kc = kcgw & 1;
      int gw = kcgw >> 1;
      g = gw >> 2; w = gw & 3;
    } else {                          // reg part: kc 2..7: 16384 + (((g*6+c6)*4+w)*64+ln)*8+e
      int rr = rem2 - 16384;
      e = rr & 7;
      int slot = rr >> 3;
      ln = slot & 63;
      int t3 = slot >> 6;
      w = t3 & 3;
      int gk = t3 >> 2;               // g*6 + c6
      g = gk / 6;
      kc = 2 + (gk % 6);
    }
    int r = g * 256 + q * 64 + w * 16 + (ln & 15);
    int k = kc * 32 + (ln >> 4) * 8 + e;
    WHH[idx] = f2bf(w_hh[(size_t)l * 262144 + (size_t)r * 256 + k]);
    return;
  }
  idx -= S5;
  if (idx < S6) FLAGS[idx] = 0;
}

// ---------------- generic bf16 GEMM:  C(MxN) = A(MxK) * B(NxK)^T + bias ----------------
// KTILES = K/64. OUTBF: 1 bf16 out, 0 fp32 out. BMODE: 1 bias[n], 2 bias[m].
// AF32: A is fp32, converted to bf16 during LDS staging.
template<int KTILES, int OUTBF, int BMODE, int AF32>
__global__ __launch_bounds__(256, 1) void gemm_bt(
    const void* __restrict__ Av, const u16* __restrict__ B, void* __restrict__ Cv,
    const float* __restrict__ bias, size_t ldc)
{
  constexpr int K = KTILES * 64;
  __shared__ __align__(16) u16 Asl[64 * 72];   // row stride 72 u16 = 9 x 16B granules
  __shared__ __align__(16) u16 Bsl[64 * 72];
  const int tid = threadIdx.x;
  const int w = tid >> 6, lane = tid & 63, lm = lane & 15, quad = lane >> 4;
  const size_t m0 = (size_t)blockIdx.y * 64, n0 = (size_t)blockIdx.x * 64;

  f32x4 acc[4];
#pragma unroll
  for (int nt = 0; nt < 4; ++nt) { f32x4 z = {0.f, 0.f, 0.f, 0.f}; acc[nt] = z; }

  for (int kb = 0; kb < KTILES; ++kb) {
    if (AF32) {
      const float* Af = (const float*)Av;
#pragma unroll
      for (int c = 0; c < 4; ++c) {   // 1024 float4 chunks, 4/thread
        int idx = c * 256 + tid;
        int row = idx >> 4, k4 = idx & 15;
        float4 v = *(const float4*)(Af + (m0 + row) * (size_t)K + kb * 64 + k4 * 4);
        u64 pv = (u64)f2bf(v.x) | ((u64)f2bf(v.y) << 16) |
                 ((u64)f2bf(v.z) << 32) | ((u64)f2bf(v.w) << 48);
        *(u64*)(&Asl[row * 72 + k4 * 4]) = pv;
      }
    } else {
      const u16* Ab = (const u16*)Av;
#pragma unroll
      for (int c = 0; c < 2; ++c) {   // 512 16B chunks, 2/thread
        int idx = c * 256 + tid;
        int row = idx >> 3, k8 = idx & 7;
        *(uint4*)(&Asl[row * 72 + k8 * 8]) =
            *(const uint4*)(Ab + (m0 + row) * (size_t)K + kb * 64 + k8 * 8);
      }
    }
#pragma unroll
    for (int c = 0; c < 2; ++c) {
      int idx = c * 256 + tid;
      int row = idx >> 3, k8 = idx & 7;
      *(uint4*)(&Bsl[row * 72 + k8 * 8]) =
          *(const uint4*)(B + (n0 + row) * (size_t)K + kb * 64 + k8 * 8);
    }
    __syncthreads();
#pragma unroll
    for (int kc = 0; kc < 2; ++kc) {
      short8 a = *(const short8*)(&Asl[(w * 16 + lm) * 72 + kc * 32 + quad * 8]);
#pragma unroll
      for (int nt = 0; nt < 4; ++nt) {
        short8 b = *(const short8*)(&Bsl[(nt * 16 + lm) * 72 + kc * 32 + quad * 8]);
        acc[nt] = __builtin_amdgcn_mfma_f32_16x16x32_bf16(a, b, acc[nt], 0, 0, 0);
      }
    }
    __syncthreads();
  }
#pragma unroll
  for (int nt = 0; nt < 4; ++nt) {
    size_t n = n0 + nt * 16 + lm;
    float bn = (BMODE == 1) ? bias[n] : 0.f;
#pragma unroll
    for (int r = 0; r < 4; ++r) {
      size_t m = m0 + w * 16 + quad * 4 + r;
      float v = acc[nt][r] + ((BMODE == 2) ? bias[m] : bn);
      if (OUTBF) ((u16*)Cv)[m * ldc + n] = f2bf(v);
      else       ((float*)Cv)[m * ldc + n] = v;
    }
  }
}

// ---------------- LSTM recurrence: 4 wgs, one per 64-wide h-chunk, chunked seq ----------------
// wg q owns gate rows {g*256 + q*64 + j}. Per absolute step sA:
// gates = xgT[., t_local] + W_hh_slice * h_full (MFMA), nonlin, c,h update;
// h published to hx[parity sA&1] via agent atomics; flags[q]=sA (release).
__global__ __launch_bounds__(256, 1) void lstm_rec(
    const u16* __restrict__ xgT,   // [1024][CN] permuted rows, row stride CN
    const u16* __restrict__ whh,   // packed, 65536 u16 per q
    u16* __restrict__ xout,        // [CN][256] bf16 chunk output
    u16* __restrict__ hx,          // [2 parity][256 j][64 b] bf16 exchange buffer
    int* __restrict__ flags,       // [4] monotone absolute-step counters
    float* __restrict__ cstb,      // [4*256 threads][16] persisted c-state
    int base)                      // absolute step offset (chunk * CS)
{
  __shared__ __align__(16) u16 Wl[16384];   // W_hh kc 0..1 fragments (32 KB)
  __shared__ __align__(16) u16 Hl[16384];   // h A-fragments (32 KB)
  const int q = blockIdx.x, tid = threadIdx.x;
  const int w = tid >> 6, lane = tid & 63, lm = lane & 15, quad = lane >> 4;
  const u16* wq = whh + (size_t)q * 65536;

#pragma unroll
  for (int c = 0; c < 8; ++c)
    ((uint4*)Wl)[c * 256 + tid] = ((const uint4*)wq)[c * 256 + tid];

  short8 wreg[4][6];                 // W_hh kc 2..7 fragments (96 VGPRs)
#pragma unroll
  for (int g = 0; g < 4; ++g)
#pragma unroll
    for (int c6 = 0; c6 < 6; ++c6)
      wreg[g][c6] = *(const short8*)(wq + 16384 +
                    (size_t)(((g * 6 + c6) * 4 + w) * 64 + lane) * 8);

  {
    uint4 z; z.x = z.y = z.z = z.w = 0u;
#pragma unroll
    for (int i = 0; i < 8; ++i) ((uint4*)Hl)[i * 256 + tid] = z;
  }
  float* cp = cstb + (size_t)(q * 256 + tid) * 16;
  f32x4 cst[4];
  if (base) {
#pragma unroll
    for (int mt = 0; mt < 4; ++mt) cst[mt] = ((const f32x4*)cp)[mt];
  } else {
#pragma unroll
    for (int mt = 0; mt < 4; ++mt) { f32x4 z4 = {0.f, 0.f, 0.f, 0.f}; cst[mt] = z4; }
  }
  const int jg = q * 64 + w * 16 + lm;             // this lane's h column
  __syncthreads();

  for (int s = 1; s <= CS; ++s) {
    const int sA = base + s;
    // ---- acc init from xgT (input projection + biases), D-fragment layout ----
    f32x4 acc[4][4];
    {
      const size_t col0 = (size_t)(s - 1) * 64 + quad * 4;
#pragma unroll
      for (int g = 0; g < 4; ++g) {
        const u16* rp = xgT + (size_t)(q * 256 + g * 64 + w * 16 + lm) * CN + col0;
#pragma unroll
        for (int mt = 0; mt < 4; ++mt) {
          u64 xv = *(const u64*)(rp + mt * 16);
          f32x4 t = { bf2f((u16)xv), bf2f((u16)(xv >> 16)),
                      bf2f((u16)(xv >> 32)), bf2f((u16)(xv >> 48)) };
          acc[g][mt] = t;
        }
      }
    }
    // ---- gather h (all 4 chunks) from hx into Hl ----
    if (sA >= 2) {
      const int need = sA - 1;
      for (int p = 0; p < 4; ++p) {
        if (p == q) continue;
        while (__hip_atomic_load(&flags[p], __ATOMIC_RELAXED, __HIP_MEMORY_SCOPE_AGENT) < need) { }
      }
      const u16* hsrc = hx + (size_t)((sA - 1) & 1) * 16384;
#pragma unroll
      for (int i = 0; i < 16; ++i) {   // 4 chunks * 64 j * 16 bquads = 4096 u64 loads
        int cidx = i * 256 + tid;
        int hk = cidx >> 4, bq = cidx & 15;
        u64 hv = __hip_atomic_load((const u64*)(hsrc + (size_t)hk * 64 + bq * 4),
                                   __ATOMIC_RELAXED, __HIP_MEMORY_SCOPE_AGENT);
        int kc = hk >> 5, q5 = (hk >> 3) & 3, e = hk & 7;
#pragma unroll
        for (int r = 0; r < 4; ++r) {
          int b = bq * 4 + r;
          Hl[(size_t)((((b >> 4) * 8 + kc) * 64 + q5 * 16 + (b & 15)) * 8 + e)] =
              (u16)(hv >> (16 * r));
        }
      }
    }
    __syncthreads();                    // Hl complete before MFMA reads
    // ---- gates += W_hh_slice * h ----
#pragma unroll
    for (int kc = 0; kc < 8; ++kc) {
      short8 af[4];
#pragma unroll
      for (int mt = 0; mt < 4; ++mt)
        af[mt] = *(const short8*)(&Hl[((mt * 8 + kc) * 64 + lane) * 8]);
#pragma unroll
      for (int g = 0; g < 4; ++g) {
        short8 bfr = (kc < 2)
            ? *(const short8*)(&Wl[(((g * 4 + w) * 2 + kc) * 64 + lane) * 8])
            : wreg[g][kc - 2];
#pragma unroll
        for (int mt = 0; mt < 4; ++mt)
          acc[g][mt] = __builtin_amdgcn_mfma_f32_16x16x32_bf16(af[mt], bfr, acc[g][mt], 0, 0, 0);
      }
    }
    // ---- nonlinearity + state update (c in fp32 regs) ----
    u16 hb[4][4];
#pragma unroll
    for (int mt = 0; mt < 4; ++mt)
#pragma unroll
      for (int r = 0; r < 4; ++r) {
        float iv = sigf(acc[0][mt][r]);
        float fv = sigf(acc[1][mt][r]);
        float gv = tanhf_fast(acc[2][mt][r]);
        float ov = sigf(acc[3][mt][r]);
        float cv = fv * cst[mt][r] + iv * gv;
        cst[mt][r] = cv;
        hb[mt][r] = f2bf(ov * tanhf_fast(cv));
      }
    // ---- publish h: atomics to hx, plain stores to xout ----
    u16* hdst = hx + (size_t)(sA & 1) * 16384;
#pragma unroll
    for (int mt = 0; mt < 4; ++mt) {
      u64 pv = (u64)hb[mt][0] | ((u64)hb[mt][1] << 16) |
               ((u64)hb[mt][2] << 32) | ((u64)hb[mt][3] << 48);
      __hip_atomic_store((u64*)(hdst + (size_t)jg * 64 + mt * 16 + quad * 4), pv,
                         __ATOMIC_RELAXED, __HIP_MEMORY_SCOPE_AGENT);
#pragma unroll
      for (int r = 0; r < 4; ++r) {
        int b = mt * 16 + quad * 4 + r;
        xout[((size_t)(s - 1) * 64 + b) * 256 + jg] = hb[mt][r];
      }
    }
    __syncthreads();   // all waves done reading Hl + stores drained before flag
    if (tid == 0)
      __hip_atomic_store(&flags[q], sA, __ATOMIC_RELEASE, __HIP_MEMORY_SCOPE_AGENT);
  }
#pragma unroll
  for (int mt = 0; mt < 4; ++mt) ((f32x4*)cp)[mt] = cst[mt];
}

// ---------------- launch ----------------
extern "C" void kernel_launch(void* const* d_in, const int* in_sizes, int n_in,
                              void* d_out, int out_size, void* d_ws, size_t ws_size,
                              hipStream_t stream)
{
  const float* in0   = (const float*)d_in[0];
  const float* enc_w = (const float*)d_in[1];
  const float* enc_b = (const float*)d_in[2];
  const float* w_ih  = (const float*)d_in[3];
  const float* w_hh  = (const float*)d_in[4];
  const float* b_ih  = (const float*)d_in[5];
  const float* b_hh  = (const float*)d_in[6];
  const float* dec_w = (const float*)d_in[7];
  const float* dec_b = (const float*)d_in[8];

  char* ws = (char*)d_ws;
  u16*   XG    = (u16*)(ws);                 // 33,554,432 B  xgT chunk [1024][CN]
  u16*   XA    = (u16*)(ws + 33554432);      //  8,388,608 B  x chunk stream A (x0/x2)
  u16*   XB    = (u16*)(ws + 41943040);      //  8,388,608 B  x chunk stream B (x1)
  u16*   WIH   = (u16*)(ws + 50331648);      //  1,048,576 B
  u16*   WHH   = (u16*)(ws + 51380224);      //  1,048,576 B
  u16*   WENC  = (u16*)(ws + 52428800);      //     32,768 B
  u16*   WDEC  = (u16*)(ws + 52461568);      //     32,768 B
  float* BIASP = (float*)(ws + 52494336);    //      8,192 B
  u16*   HX    = (u16*)(ws + 52502528);      //    131,072 B (2 layers x 65536)
  float* CST   = (float*)(ws + 52633600);    //    131,072 B (2 layers x 65536)
  int*   FLAGS = (int*)(ws + 52764672);      //         64 B

  if (ws_size < 52764736) return;   // diagnostic guard: fail absmax, not fault

  prep_kernel<<<dim3((PREP_TOTAL + 255) / 256), 256, 0, stream>>>(
      enc_w, w_ih, w_hh, b_ih, b_hh, dec_w,
      WENC, WDEC, WIH, BIASP, WHH, FLAGS);

  for (int c = 0; c < NCH; ++c) {
    const float* inc = in0 + (size_t)c * CN * 64;
    float* outc = (float*)d_out + (size_t)c * CN * 64;
    // encoder: x0c = inc @ enc_w^T + enc_b   (M=CN, N=256, K=64)
    gemm_bt<1, 1, 1, 1><<<dim3(4, CN / 64), 256, 0, stream>>>(inc, WENC, XA, enc_b, 256);
    // layer 0: xgT = W_ih0_perm @ x0c^T + bias  (M=1024, N=CN, K=256)
    gemm_bt<4, 1, 2, 0><<<dim3(CN / 64, 16), 256, 0, stream>>>(WIH, XA, XG, BIASP, CN);
    lstm_rec<<<dim3(4), 256, 0, stream>>>(XG, WHH, XB, HX, FLAGS, CST, c * CS);
    // layer 1
    gemm_bt<4, 1, 2, 0><<<dim3(CN / 64, 16), 256, 0, stream>>>(WIH + 262144, XB, XG, BIASP + 1024, CN);
    lstm_rec<<<dim3(4), 256, 0, stream>>>(XG, WHH + 262144, XA, HX + 32768, FLAGS + 4, CST + 16384, c * CS);
    // decoder: outc = x2c @ dec_w^T + dec_b  (M=CN, N=64, K=256), fp32 out
    gemm_bt<4, 0, 1, 0><<<dim3(1, CN / 64), 256, 0, stream>>>(XA, WDEC, (void*)outc, dec_b, 64);
  }

  (void)in_sizes; (void)n_in; (void)out_size;
}